// Round 6
// baseline (877.756 us; speedup 1.0000x reference)
//
#include <hip/hip_runtime.h>
#include <hip/hip_bf16.h>

#define N_NODES 50000
#define N_EDGES 1600000
#define N_GRAPHS 64
#define D_IN 128
#define D_H 512
#define D_OUT 16

#define SCAN_BLOCKS ((N_NODES + 255) / 256)      // 196

// bucket scatter: 512-row buckets, 8 edge-chunks per bucket, XCD-pinned.
#define BUCKET_ROWS 512
#define BQ 13                                     // 13*8 = 104 bucket slots >= 98 needed
#define SCAT_CHUNKS 8
#define EDGES_PER_CHUNK (N_EDGES / SCAT_CHUNKS)   // 200000

typedef short bf16x8 __attribute__((ext_vector_type(8)));
typedef float f32x4 __attribute__((ext_vector_type(4)));

static __device__ __forceinline__ unsigned short f2bf(float f) {
    __hip_bfloat16 h = __float2bfloat16(f);   // RNE
    return *(unsigned short*)&h;
}

// ---------------------------------------------------------------- CSR build

__global__ __launch_bounds__(256) void count_deg(const int* __restrict__ row,
                                                 int* __restrict__ deg, int n) {
    int i = blockIdx.x * 256 + threadIdx.x;
    if (i < n) atomicAdd(&deg[row[i]], 1);
}

// batch is SORTED: gcnt[g] = lower_bound(g+1) - lower_bound(g). 64 threads, no atomics.
__global__ __launch_bounds__(64) void graph_counts(const int* __restrict__ batch,
                                                   int* __restrict__ gcnt) {
    int g = threadIdx.x;
    int lo = 0, hi = N_NODES;
    while (lo < hi) { int mid = (lo + hi) >> 1; if (batch[mid] < g) lo = mid + 1; else hi = mid; }
    int a = lo;
    lo = 0; hi = N_NODES;
    while (lo < hi) { int mid = (lo + hi) >> 1; if (batch[mid] < g + 1) lo = mid + 1; else hi = mid; }
    gcnt[g] = lo - a;
}

// ---- multi-block scan: (1) per-block sums, (2) scan sums, (3) write rowptr

__global__ __launch_bounds__(256) void scan_phase1(const int* __restrict__ deg,
                                                   int* __restrict__ psum) {
    __shared__ int sh[256];
    int tid = threadIdx.x;
    int i = blockIdx.x * 256 + tid;
    sh[tid] = (i < N_NODES) ? deg[i] : 0;
    __syncthreads();
    for (int off = 128; off > 0; off >>= 1) {
        if (tid < off) sh[tid] += sh[tid + off];
        __syncthreads();
    }
    if (tid == 0) psum[blockIdx.x] = sh[0];
}

__global__ __launch_bounds__(256) void scan_phase2(int* __restrict__ psum) {
    __shared__ int sh[256];
    int tid = threadIdx.x;
    sh[tid] = (tid < SCAN_BLOCKS) ? psum[tid] : 0;
    __syncthreads();
    for (int off = 1; off < 256; off <<= 1) {
        int v = (tid >= off) ? sh[tid - off] : 0;
        __syncthreads();
        sh[tid] += v;
        __syncthreads();
    }
    // exclusive: psum[t] = inclusive[t-1], psum[0] = 0
    if (tid < SCAN_BLOCKS) psum[tid] = (tid == 0) ? 0 : sh[tid - 1];
}

__global__ __launch_bounds__(256) void scan_phase3(const int* __restrict__ deg,
                                                   const int* __restrict__ psum,
                                                   int* __restrict__ rowptr,
                                                   float* __restrict__ invdeg) {
    __shared__ int sh[256];
    int tid = threadIdx.x;
    int i = blockIdx.x * 256 + tid;
    int v = (i < N_NODES) ? deg[i] : 0;
    sh[tid] = v;
    __syncthreads();
    for (int off = 1; off < 256; off <<= 1) {
        int t = (tid >= off) ? sh[tid - off] : 0;
        __syncthreads();
        sh[tid] += t;
        __syncthreads();
    }
    int incl = sh[tid];
    int base = psum[blockIdx.x];
    if (i < N_NODES) {
        rowptr[i] = base + incl - v;
        invdeg[i] = 1.0f / (float)(v + 1);
        if (i == N_NODES - 1) rowptr[N_NODES] = base + incl;
    }
}

// XCD-pinned bucket scatter. Bucket = 512 consecutive rows -> ~64KB contiguous
// csr_col window. All 8 chunk-blocks of one bucket share blk&7 -> same XCD under
// the round-robin block->XCD heuristic, so the window lives in ONE L2 and
// write-backs are full dirty lines (perf heuristic only; correct regardless).
__global__ __launch_bounds__(256) void bucket_scatter(const int* __restrict__ row,
                                                      const int* __restrict__ col,
                                                      const int* __restrict__ rowptr,
                                                      int* __restrict__ cursor,
                                                      int* __restrict__ csr_col) {
    int blk = blockIdx.x;
    int br = blk & 7;
    int t = blk >> 3;
    int bq = t % BQ;
    int c  = t / BQ;
    int bucket = bq * 8 + br;                 // 0..103; buckets >= 98 match no rows
    int rlo = bucket * BUCKET_ROWS;
    int e1 = (c + 1) * EDGES_PER_CHUNK;
    for (int i = c * EDGES_PER_CHUNK + threadIdx.x; i < e1; i += 256) {
        int r = row[i];
        if ((unsigned)(r - rlo) < (unsigned)BUCKET_ROWS) {
            int pos = rowptr[r] + atomicAdd(&cursor[r], 1);
            csr_col[pos] = col[i];
        }
    }
}

// ---------------------------------------------------------------- converts

// x f32 [N][128] -> packed bf16x2 [N][64]
__global__ __launch_bounds__(256) void convert_x(const float* __restrict__ x,
                                                 unsigned* __restrict__ xb, int npairs) {
    int i = blockIdx.x * 256 + threadIdx.x;
    if (i < npairs) {
        float2 v = ((const float2*)x)[i];
        xb[i] = (unsigned)f2bf(v.x) | ((unsigned)f2bf(v.y) << 16);
    }
}

// w1 f32 [128][512] -> bf16 pre-swizzled to MFMA B-frag order: [t(32)][s(4)][lane(64)][j(8)]
// B[k = s*32 + (lane>>4)*8 + j][n = t*16 + (lane&15)]
__global__ __launch_bounds__(256) void make_w1p(const float* __restrict__ w1,
                                                unsigned short* __restrict__ w1p) {
    int i = blockIdx.x * 256 + threadIdx.x;     // 65536 total
    int j = i & 7, lane = (i >> 3) & 63, s = (i >> 9) & 3, t = i >> 11;
    int k = s * 32 + (lane >> 4) * 8 + j;
    int n = t * 16 + (lane & 15);
    w1p[i] = f2bf(w1[(size_t)k * D_H + n]);
}

// ---------------------------------------------------------------- propagation (bf16 storage, f32 accumulate)
// out[r] = (x[r] + sum_{r->c} x[c]) * invdeg[r]
// 4 waves/block, one row per wave; col indices shfl-broadcast from lane regs
// (no LDS, no barriers); 8 independent 256B gathers in flight.

__global__ __launch_bounds__(256) void propagate_bf16(const unsigned* __restrict__ xin,
                                                      unsigned* __restrict__ xout,
                                                      const int* __restrict__ rowptr,
                                                      const int* __restrict__ csr_col,
                                                      const float* __restrict__ invdeg) {
    int wave = threadIdx.x >> 6;
    int lane = threadIdx.x & 63;
    int r = blockIdx.x * 4 + wave;
    if (r >= N_NODES) return;
    int beg = rowptr[r], end = rowptr[r + 1];
    unsigned u = xin[(size_t)r * 64 + lane];      // self loop
    float acc0 = __uint_as_float(u << 16);
    float acc1 = __uint_as_float(u & 0xffff0000u);
    for (int cs = beg; cs < end; cs += 64) {
        int nn = end - cs; if (nn > 64) nn = 64;
        int idx = cs + (lane < nn ? lane : 0);
        int colv = csr_col[idx];
        int j = 0;
        for (; j + 8 <= nn; j += 8) {
            int c0 = __shfl(colv, j + 0, 64), c1 = __shfl(colv, j + 1, 64);
            int c2 = __shfl(colv, j + 2, 64), c3 = __shfl(colv, j + 3, 64);
            int c4 = __shfl(colv, j + 4, 64), c5 = __shfl(colv, j + 5, 64);
            int c6 = __shfl(colv, j + 6, 64), c7 = __shfl(colv, j + 7, 64);
            unsigned u0 = xin[(size_t)c0 * 64 + lane];
            unsigned u1 = xin[(size_t)c1 * 64 + lane];
            unsigned u2 = xin[(size_t)c2 * 64 + lane];
            unsigned u3 = xin[(size_t)c3 * 64 + lane];
            unsigned u4 = xin[(size_t)c4 * 64 + lane];
            unsigned u5 = xin[(size_t)c5 * 64 + lane];
            unsigned u6 = xin[(size_t)c6 * 64 + lane];
            unsigned u7 = xin[(size_t)c7 * 64 + lane];
            acc0 += __uint_as_float(u0 << 16) + __uint_as_float(u1 << 16)
                  + __uint_as_float(u2 << 16) + __uint_as_float(u3 << 16)
                  + __uint_as_float(u4 << 16) + __uint_as_float(u5 << 16)
                  + __uint_as_float(u6 << 16) + __uint_as_float(u7 << 16);
            acc1 += __uint_as_float(u0 & 0xffff0000u) + __uint_as_float(u1 & 0xffff0000u)
                  + __uint_as_float(u2 & 0xffff0000u) + __uint_as_float(u3 & 0xffff0000u)
                  + __uint_as_float(u4 & 0xffff0000u) + __uint_as_float(u5 & 0xffff0000u)
                  + __uint_as_float(u6 & 0xffff0000u) + __uint_as_float(u7 & 0xffff0000u);
        }
        for (; j < nn; ++j) {
            int c = __shfl(colv, j, 64);
            unsigned uu = xin[(size_t)c * 64 + lane];
            acc0 += __uint_as_float(uu << 16);
            acc1 += __uint_as_float(uu & 0xffff0000u);
        }
    }
    float inv = invdeg[r];
    acc0 *= inv; acc1 *= inv;
    xout[(size_t)r * 64 + lane] = (unsigned)f2bf(acc0) | ((unsigned)f2bf(acc1) << 16);
}

// ---------------------------------------------------------------- MFMA GEMM (h3 @ w1) + bias + ReLU + segmented pool
// block 256 = 4 waves; tile M=64, N=128; K=128 (4 steps of 32).
// A[m=lane&15][k=quad*8+j] direct from bf16 h3; B pre-swizzled; C: col=lane&15, row=quad*4+reg.

__global__ __launch_bounds__(256) void gemm_mfma_pool(const unsigned short* __restrict__ h3b,
                                                      const unsigned short* __restrict__ w1p,
                                                      const float* __restrict__ b1,
                                                      const int* __restrict__ batch,
                                                      float* __restrict__ gsum) {
    __shared__ float hls[64][132];   // +4 pad: conflict-free row-strided writes
    __shared__ int bls[64];
    int tid = threadIdx.x;
    int lane = tid & 63, wave = tid >> 6;
    int quad = lane >> 4, l15 = lane & 15;
    int mbase = blockIdx.x * 64;
    int nbase = blockIdx.y * 128;

    int m = mbase + wave * 16 + l15;
    int mc = m < N_NODES ? m : N_NODES - 1;          // clamp; garbage rows skipped in epilogue
    const unsigned short* arow = h3b + (size_t)mc * 128 + quad * 8;
    bf16x8 afrag[4];
#pragma unroll
    for (int s = 0; s < 4; ++s)
        afrag[s] = *(const bf16x8*)(arow + s * 32);

    f32x4 acc[8];
#pragma unroll
    for (int t = 0; t < 8; ++t) acc[t] = (f32x4){0.f, 0.f, 0.f, 0.f};

    const unsigned short* bbase = w1p + ((size_t)(blockIdx.y * 8) * 4 * 64 + lane) * 8;
#pragma unroll
    for (int t = 0; t < 8; ++t) {
#pragma unroll
        for (int s = 0; s < 4; ++s) {
            bf16x8 bfrag = *(const bf16x8*)(bbase + (size_t)(t * 4 + s) * 64 * 8);
            acc[t] = __builtin_amdgcn_mfma_f32_16x16x32_bf16(afrag[s], bfrag, acc[t], 0, 0, 0);
        }
    }

    if (tid < 64) {
        int mm = mbase + tid;
        bls[tid] = (mm < N_NODES) ? batch[mm] : 0;
    }
#pragma unroll
    for (int t = 0; t < 8; ++t)
#pragma unroll
        for (int rg = 0; rg < 4; ++rg)
            hls[wave * 16 + quad * 4 + rg][t * 16 + l15] = acc[t][rg];
    __syncthreads();

    // epilogue: bias + relu + sorted-segment pool; thread owns (col, 32-row half)
    int c = tid & 127, half = tid >> 7;
    float bias = b1[nbase + c];
    int r0 = half * 32;
    int cur = bls[r0];
    float s = 0.f;
    for (int r = r0; r < r0 + 32; ++r) {
        int mm = mbase + r;
        if (mm >= N_NODES) break;
        int g = bls[r];
        float v = hls[r][c] + bias;
        v = v > 0.f ? v : 0.f;
        if (g != cur) { atomicAdd(&gsum[cur * D_H + nbase + c], s); s = 0.f; cur = g; }
        s += v;
    }
    atomicAdd(&gsum[cur * D_H + nbase + c], s);
}

// ---------------------------------------------------------------- final: mean + (512x512) + (512x16), one block per graph

__global__ __launch_bounds__(256) void final_mlp(const float* __restrict__ gsum,
                                                 const int* __restrict__ gcnt,
                                                 const float* __restrict__ w2,
                                                 const float* __restrict__ b2,
                                                 const float* __restrict__ wc,
                                                 const float* __restrict__ bc,
                                                 float* __restrict__ out) {
    int g = blockIdx.x;
    int tid = threadIdx.x;
    __shared__ float p[D_H];
    __shared__ float h5s[D_H];
    int c = gcnt[g]; if (c < 1) c = 1;
    float inv = 1.0f / (float)c;
    for (int i = tid; i < D_H; i += 256) p[i] = gsum[g * D_H + i] * inv;
    __syncthreads();
    float a0 = b2[tid], a1 = b2[tid + 256];
    for (int k = 0; k < D_H; ++k) {
        float pv = p[k];
        a0 += pv * w2[(size_t)k * D_H + tid];
        a1 += pv * w2[(size_t)k * D_H + tid + 256];
    }
    h5s[tid] = a0; h5s[tid + 256] = a1;
    __syncthreads();
    if (tid < D_OUT) {
        float s = bc[tid];
        for (int k = 0; k < D_H; ++k) s += h5s[k] * wc[(size_t)k * D_OUT + tid];
        out[g * D_OUT + tid] = s;
    }
}

// ---------------------------------------------------------------- launch

extern "C" void kernel_launch(void* const* d_in, const int* in_sizes, int n_in,
                              void* d_out, int out_size, void* d_ws, size_t ws_size,
                              hipStream_t stream) {
    const float* x     = (const float*)d_in[0];
    const int*   eidx  = (const int*)d_in[1];   // [2, E]
    const int*   batch = (const int*)d_in[2];
    const float* w1    = (const float*)d_in[3];
    const float* b1    = (const float*)d_in[4];
    const float* w2    = (const float*)d_in[5];
    const float* b2    = (const float*)d_in[6];
    const float* wc    = (const float*)d_in[7];
    const float* bc    = (const float*)d_in[8];
    float* out = (float*)d_out;
    const int* row = eidx;
    const int* col = eidx + N_EDGES;

    char* p = (char*)d_ws;
    auto alloc = [&](size_t bytes) { char* q = p; p += (bytes + 255) & ~(size_t)255; return q; };
    // zero-init region: deg, cursor, gsum contiguous -> ONE memset
    char* zbase = p;
    int*   deg     = (int*)alloc((size_t)N_NODES * 4);
    int*   cursor  = (int*)alloc((size_t)N_NODES * 4);
    float* gsum    = (float*)alloc((size_t)N_GRAPHS * D_H * 4);
    size_t zbytes = (size_t)(p - zbase);
    int*   rowptr  = (int*)alloc((size_t)(N_NODES + 1) * 4);
    int*   psum    = (int*)alloc((size_t)SCAN_BLOCKS * 4);
    int*   gcnt    = (int*)alloc((size_t)N_GRAPHS * 4);
    float* invdeg  = (float*)alloc((size_t)N_NODES * 4);
    int*   csr_col = (int*)alloc((size_t)N_EDGES * 4);
    unsigned* xb   = (unsigned*)alloc((size_t)N_NODES * 64 * 4);   // bf16x2 packed
    unsigned* h0b  = (unsigned*)alloc((size_t)N_NODES * 64 * 4);
    unsigned* h1b  = (unsigned*)alloc((size_t)N_NODES * 64 * 4);
    unsigned short* w1p = (unsigned short*)alloc((size_t)D_IN * D_H * 2);

    (void)hipMemsetAsync(zbase, 0, zbytes, stream);

    convert_x<<<(N_NODES * 64 + 255) / 256, 256, 0, stream>>>(x, xb, N_NODES * 64);
    make_w1p<<<(D_IN * D_H) / 256, 256, 0, stream>>>(w1, w1p);

    count_deg<<<(N_EDGES + 255) / 256, 256, 0, stream>>>(row, deg, N_EDGES);
    graph_counts<<<1, 64, 0, stream>>>(batch, gcnt);

    scan_phase1<<<SCAN_BLOCKS, 256, 0, stream>>>(deg, psum);
    scan_phase2<<<1, 256, 0, stream>>>(psum);
    scan_phase3<<<SCAN_BLOCKS, 256, 0, stream>>>(deg, psum, rowptr, invdeg);

    bucket_scatter<<<SCAT_CHUNKS * BQ * 8, 256, 0, stream>>>(row, col, rowptr, cursor, csr_col);

    propagate_bf16<<<(N_NODES + 3) / 4, 256, 0, stream>>>(xb,  h0b, rowptr, csr_col, invdeg);
    propagate_bf16<<<(N_NODES + 3) / 4, 256, 0, stream>>>(h0b, h1b, rowptr, csr_col, invdeg);
    propagate_bf16<<<(N_NODES + 3) / 4, 256, 0, stream>>>(h1b, h0b, rowptr, csr_col, invdeg);

    dim3 ggrid((N_NODES + 63) / 64, D_H / 128);
    gemm_mfma_pool<<<ggrid, 256, 0, stream>>>((const unsigned short*)h0b, w1p, b1, batch, gsum);
    final_mlp<<<N_GRAPHS, 256, 0, stream>>>(gsum, gcnt, w2, b2, wc, bc, out);
}

// Round 7
// 369.191 us; speedup vs baseline: 2.3775x; 2.3775x over previous
//
#include <hip/hip_runtime.h>
#include <hip/hip_bf16.h>

#define N_NODES 50000
#define N_EDGES 1600000
#define N_GRAPHS 64
#define D_IN 128
#define D_H 512
#define D_OUT 16

// atomic-free CSR build: buckets of 256 rows
#define NBUK 196                      // ceil(50000/256)
#define BUK_CAP 9216                  // per-bucket capacity: mean 8192 + ~11 sigma
#define P1_EDGES 8192                 // edges per partition block
#define P1_BLOCKS ((N_EDGES + P1_EDGES - 1) / P1_EDGES)   // 196

typedef short bf16x8 __attribute__((ext_vector_type(8)));
typedef float f32x4 __attribute__((ext_vector_type(4)));

static __device__ __forceinline__ unsigned short f2bf(float f) {
    __hip_bfloat16 h = __float2bfloat16(f);   // RNE
    return *(unsigned short*)&h;
}

// batch is SORTED: gcnt[g] = lower_bound(g+1) - lower_bound(g). 64 threads, no atomics.
__global__ __launch_bounds__(64) void graph_counts(const int* __restrict__ batch,
                                                   int* __restrict__ gcnt) {
    int g = threadIdx.x;
    int lo = 0, hi = N_NODES;
    while (lo < hi) { int mid = (lo + hi) >> 1; if (batch[mid] < g) lo = mid + 1; else hi = mid; }
    int a = lo;
    lo = 0; hi = N_NODES;
    while (lo < hi) { int mid = (lo + hi) >> 1; if (batch[mid] < g + 1) lo = mid + 1; else hi = mid; }
    gcnt[g] = lo - a;
}

// ---------------------------------------------------------------- CSR build (atomic-free)
// P1: partition edges into 196 buckets of 256 rows. Packed rec = (buk<<24)|(r_low<<16)|col.
// Only 196 global atomics per block (range reservation); ranking via LDS atomics.

__global__ __launch_bounds__(256) void partition_edges(const int* __restrict__ row,
                                                       const int* __restrict__ col,
                                                       int* __restrict__ bucket_cnt,
                                                       unsigned* __restrict__ edge_buf) {
    __shared__ unsigned recs[P1_EDGES];     // 32 KB
    __shared__ unsigned sorted[P1_EDGES];   // 32 KB
    __shared__ int hist[NBUK];              // counts, then repurposed as local excl base
    __shared__ int cur[NBUK];
    __shared__ int gbase[NBUK];
    __shared__ int scan[256];
    int tid = threadIdx.x;
    int e0 = blockIdx.x * P1_EDGES;
    int m = N_EDGES - e0; if (m > P1_EDGES) m = P1_EDGES;

    for (int i = tid; i < NBUK; i += 256) { hist[i] = 0; cur[i] = 0; }
    __syncthreads();
    for (int i = tid; i < m; i += 256) {
        int r = row[e0 + i];
        int c = col[e0 + i];
        int buk = r >> 8;
        recs[i] = ((unsigned)buk << 24) | ((unsigned)(r & 255) << 16) | (unsigned)c;
        atomicAdd(&hist[buk], 1);
    }
    __syncthreads();
    scan[tid] = (tid < NBUK) ? hist[tid] : 0;
    __syncthreads();
    for (int off = 1; off < 256; off <<= 1) {
        int v = (tid >= off) ? scan[tid - off] : 0;
        __syncthreads();
        scan[tid] += v;
        __syncthreads();
    }
    if (tid < NBUK) {
        int cnt = hist[tid];
        hist[tid] = (tid == 0) ? 0 : scan[tid - 1];            // local excl base
        gbase[tid] = (cnt > 0) ? atomicAdd(&bucket_cnt[tid], cnt) : 0;  // reserve range
    }
    __syncthreads();
    for (int i = tid; i < m; i += 256) {                       // rank + reorder (bucket-major)
        unsigned rec = recs[i];
        int buk = rec >> 24;
        int rank = atomicAdd(&cur[buk], 1);
        sorted[hist[buk] + rank] = rec;
    }
    __syncthreads();
    for (int p = tid; p < m; p += 256) {                       // coalesced-run writes
        unsigned rec = sorted[p];
        int buk = rec >> 24;
        edge_buf[(size_t)buk * BUK_CAP + gbase[buk] + (p - hist[buk])] = rec;
    }
}

__global__ __launch_bounds__(256) void scan_buckets(const int* __restrict__ bucket_cnt,
                                                    int* __restrict__ bucket_base) {
    __shared__ int scan[256];
    int tid = threadIdx.x;
    scan[tid] = (tid < NBUK) ? bucket_cnt[tid] : 0;
    __syncthreads();
    for (int off = 1; off < 256; off <<= 1) {
        int v = (tid >= off) ? scan[tid - off] : 0;
        __syncthreads();
        scan[tid] += v;
        __syncthreads();
    }
    if (tid < NBUK) bucket_base[tid] = (tid == 0) ? 0 : scan[tid - 1];
}

// P2: one block per bucket. LDS hist+scan -> rowptr/invdeg; LDS-cursor scatter into the
// bucket's contiguous 32KB csr_col window (single block -> single XCD -> full-line writebacks).
__global__ __launch_bounds__(256) void finalize_csr(const unsigned* __restrict__ edge_buf,
                                                    const int* __restrict__ bucket_cnt,
                                                    const int* __restrict__ bucket_base,
                                                    int* __restrict__ rowptr,
                                                    float* __restrict__ invdeg,
                                                    int* __restrict__ csr_col) {
    __shared__ int hist[256], excl[256], cur[256], scan[256];
    int b = blockIdx.x;
    int tid = threadIdx.x;
    int cnt = bucket_cnt[b];
    int base = bucket_base[b];
    const unsigned* src = edge_buf + (size_t)b * BUK_CAP;
    hist[tid] = 0; cur[tid] = 0;
    __syncthreads();
    for (int i = tid; i < cnt; i += 256)
        atomicAdd(&hist[(src[i] >> 16) & 255], 1);
    __syncthreads();
    scan[tid] = hist[tid];
    __syncthreads();
    for (int off = 1; off < 256; off <<= 1) {
        int v = (tid >= off) ? scan[tid - off] : 0;
        __syncthreads();
        scan[tid] += v;
        __syncthreads();
    }
    excl[tid] = (tid == 0) ? 0 : scan[tid - 1];
    __syncthreads();
    int r = b * 256 + tid;
    if (r < N_NODES) {
        rowptr[r] = base + excl[tid];
        invdeg[r] = 1.0f / (float)(hist[tid] + 1);   // +1: self loop
    }
    if (b == NBUK - 1 && tid == 0) rowptr[N_NODES] = base + cnt;
    for (int i = tid; i < cnt; i += 256) {
        unsigned rec = src[i];
        int rl = (rec >> 16) & 255;
        int pos = excl[rl] + atomicAdd(&cur[rl], 1);
        csr_col[base + pos] = (int)(rec & 0xFFFFu);
    }
}

// ---------------------------------------------------------------- converts

// x f32 [N][128] -> packed bf16x2 [N][64]
__global__ __launch_bounds__(256) void convert_x(const float* __restrict__ x,
                                                 unsigned* __restrict__ xb, int npairs) {
    int i = blockIdx.x * 256 + threadIdx.x;
    if (i < npairs) {
        float2 v = ((const float2*)x)[i];
        xb[i] = (unsigned)f2bf(v.x) | ((unsigned)f2bf(v.y) << 16);
    }
}

// w1 f32 [128][512] -> bf16 pre-swizzled to MFMA B-frag order: [t(32)][s(4)][lane(64)][j(8)]
// B[k = s*32 + (lane>>4)*8 + j][n = t*16 + (lane&15)]
__global__ __launch_bounds__(256) void make_w1p(const float* __restrict__ w1,
                                                unsigned short* __restrict__ w1p) {
    int i = blockIdx.x * 256 + threadIdx.x;     // 65536 total
    int j = i & 7, lane = (i >> 3) & 63, s = (i >> 9) & 3, t = i >> 11;
    int k = s * 32 + (lane >> 4) * 8 + j;
    int n = t * 16 + (lane & 15);
    w1p[i] = f2bf(w1[(size_t)k * D_H + n]);
}

// ---------------------------------------------------------------- propagation (bf16 storage, f32 accumulate)
// out[r] = (x[r] + sum_{r->c} x[c]) * invdeg[r]
// 4 waves/block, one row per wave; col indices shfl-broadcast from lane regs
// (no LDS, no barriers); 8 independent 256B gathers in flight.

__global__ __launch_bounds__(256) void propagate_bf16(const unsigned* __restrict__ xin,
                                                      unsigned* __restrict__ xout,
                                                      const int* __restrict__ rowptr,
                                                      const int* __restrict__ csr_col,
                                                      const float* __restrict__ invdeg) {
    int wave = threadIdx.x >> 6;
    int lane = threadIdx.x & 63;
    int r = blockIdx.x * 4 + wave;
    if (r >= N_NODES) return;
    int beg = rowptr[r], end = rowptr[r + 1];
    unsigned u = xin[(size_t)r * 64 + lane];      // self loop
    float acc0 = __uint_as_float(u << 16);
    float acc1 = __uint_as_float(u & 0xffff0000u);
    for (int cs = beg; cs < end; cs += 64) {
        int nn = end - cs; if (nn > 64) nn = 64;
        int idx = cs + (lane < nn ? lane : 0);
        int colv = csr_col[idx];
        int j = 0;
        for (; j + 8 <= nn; j += 8) {
            int c0 = __shfl(colv, j + 0, 64), c1 = __shfl(colv, j + 1, 64);
            int c2 = __shfl(colv, j + 2, 64), c3 = __shfl(colv, j + 3, 64);
            int c4 = __shfl(colv, j + 4, 64), c5 = __shfl(colv, j + 5, 64);
            int c6 = __shfl(colv, j + 6, 64), c7 = __shfl(colv, j + 7, 64);
            unsigned u0 = xin[(size_t)c0 * 64 + lane];
            unsigned u1 = xin[(size_t)c1 * 64 + lane];
            unsigned u2 = xin[(size_t)c2 * 64 + lane];
            unsigned u3 = xin[(size_t)c3 * 64 + lane];
            unsigned u4 = xin[(size_t)c4 * 64 + lane];
            unsigned u5 = xin[(size_t)c5 * 64 + lane];
            unsigned u6 = xin[(size_t)c6 * 64 + lane];
            unsigned u7 = xin[(size_t)c7 * 64 + lane];
            acc0 += __uint_as_float(u0 << 16) + __uint_as_float(u1 << 16)
                  + __uint_as_float(u2 << 16) + __uint_as_float(u3 << 16)
                  + __uint_as_float(u4 << 16) + __uint_as_float(u5 << 16)
                  + __uint_as_float(u6 << 16) + __uint_as_float(u7 << 16);
            acc1 += __uint_as_float(u0 & 0xffff0000u) + __uint_as_float(u1 & 0xffff0000u)
                  + __uint_as_float(u2 & 0xffff0000u) + __uint_as_float(u3 & 0xffff0000u)
                  + __uint_as_float(u4 & 0xffff0000u) + __uint_as_float(u5 & 0xffff0000u)
                  + __uint_as_float(u6 & 0xffff0000u) + __uint_as_float(u7 & 0xffff0000u);
        }
        for (; j < nn; ++j) {
            int c = __shfl(colv, j, 64);
            unsigned uu = xin[(size_t)c * 64 + lane];
            acc0 += __uint_as_float(uu << 16);
            acc1 += __uint_as_float(uu & 0xffff0000u);
        }
    }
    float inv = invdeg[r];
    acc0 *= inv; acc1 *= inv;
    xout[(size_t)r * 64 + lane] = (unsigned)f2bf(acc0) | ((unsigned)f2bf(acc1) << 16);
}

// ---------------------------------------------------------------- MFMA GEMM (h3 @ w1) + bias + ReLU + segmented pool
// block 256 = 4 waves; tile M=64, N=128; K=128 (4 steps of 32).
// A[m=lane&15][k=quad*8+j] direct from bf16 h3; B pre-swizzled; C: col=lane&15, row=quad*4+reg.

__global__ __launch_bounds__(256) void gemm_mfma_pool(const unsigned short* __restrict__ h3b,
                                                      const unsigned short* __restrict__ w1p,
                                                      const float* __restrict__ b1,
                                                      const int* __restrict__ batch,
                                                      float* __restrict__ gsum) {
    __shared__ float hls[64][132];   // +4 pad: conflict-free row-strided writes
    __shared__ int bls[64];
    int tid = threadIdx.x;
    int lane = tid & 63, wave = tid >> 6;
    int quad = lane >> 4, l15 = lane & 15;
    int mbase = blockIdx.x * 64;
    int nbase = blockIdx.y * 128;

    int m = mbase + wave * 16 + l15;
    int mc = m < N_NODES ? m : N_NODES - 1;          // clamp; garbage rows skipped in epilogue
    const unsigned short* arow = h3b + (size_t)mc * 128 + quad * 8;
    bf16x8 afrag[4];
#pragma unroll
    for (int s = 0; s < 4; ++s)
        afrag[s] = *(const bf16x8*)(arow + s * 32);

    f32x4 acc[8];
#pragma unroll
    for (int t = 0; t < 8; ++t) acc[t] = (f32x4){0.f, 0.f, 0.f, 0.f};

    const unsigned short* bbase = w1p + ((size_t)(blockIdx.y * 8) * 4 * 64 + lane) * 8;
#pragma unroll
    for (int t = 0; t < 8; ++t) {
#pragma unroll
        for (int s = 0; s < 4; ++s) {
            bf16x8 bfrag = *(const bf16x8*)(bbase + (size_t)(t * 4 + s) * 64 * 8);
            acc[t] = __builtin_amdgcn_mfma_f32_16x16x32_bf16(afrag[s], bfrag, acc[t], 0, 0, 0);
        }
    }

    if (tid < 64) {
        int mm = mbase + tid;
        bls[tid] = (mm < N_NODES) ? batch[mm] : 0;
    }
#pragma unroll
    for (int t = 0; t < 8; ++t)
#pragma unroll
        for (int rg = 0; rg < 4; ++rg)
            hls[wave * 16 + quad * 4 + rg][t * 16 + l15] = acc[t][rg];
    __syncthreads();

    // epilogue: bias + relu + sorted-segment pool; thread owns (col, 32-row half)
    int c = tid & 127, half = tid >> 7;
    float bias = b1[nbase + c];
    int r0 = half * 32;
    int cur = bls[r0];
    float s = 0.f;
    for (int r = r0; r < r0 + 32; ++r) {
        int mm = mbase + r;
        if (mm >= N_NODES) break;
        int g = bls[r];
        float v = hls[r][c] + bias;
        v = v > 0.f ? v : 0.f;
        if (g != cur) { atomicAdd(&gsum[cur * D_H + nbase + c], s); s = 0.f; cur = g; }
        s += v;
    }
    atomicAdd(&gsum[cur * D_H + nbase + c], s);
}

// ---------------------------------------------------------------- final: mean + (512x512) + (512x16), one block per graph

__global__ __launch_bounds__(256) void final_mlp(const float* __restrict__ gsum,
                                                 const int* __restrict__ gcnt,
                                                 const float* __restrict__ w2,
                                                 const float* __restrict__ b2,
                                                 const float* __restrict__ wc,
                                                 const float* __restrict__ bc,
                                                 float* __restrict__ out) {
    int g = blockIdx.x;
    int tid = threadIdx.x;
    __shared__ float p[D_H];
    __shared__ float h5s[D_H];
    int c = gcnt[g]; if (c < 1) c = 1;
    float inv = 1.0f / (float)c;
    for (int i = tid; i < D_H; i += 256) p[i] = gsum[g * D_H + i] * inv;
    __syncthreads();
    float a0 = b2[tid], a1 = b2[tid + 256];
    for (int k = 0; k < D_H; ++k) {
        float pv = p[k];
        a0 += pv * w2[(size_t)k * D_H + tid];
        a1 += pv * w2[(size_t)k * D_H + tid + 256];
    }
    h5s[tid] = a0; h5s[tid + 256] = a1;
    __syncthreads();
    if (tid < D_OUT) {
        float s = bc[tid];
        for (int k = 0; k < D_H; ++k) s += h5s[k] * wc[(size_t)k * D_OUT + tid];
        out[g * D_OUT + tid] = s;
    }
}

// ---------------------------------------------------------------- launch

extern "C" void kernel_launch(void* const* d_in, const int* in_sizes, int n_in,
                              void* d_out, int out_size, void* d_ws, size_t ws_size,
                              hipStream_t stream) {
    const float* x     = (const float*)d_in[0];
    const int*   eidx  = (const int*)d_in[1];   // [2, E]
    const int*   batch = (const int*)d_in[2];
    const float* w1    = (const float*)d_in[3];
    const float* b1    = (const float*)d_in[4];
    const float* w2    = (const float*)d_in[5];
    const float* b2    = (const float*)d_in[6];
    const float* wc    = (const float*)d_in[7];
    const float* bc    = (const float*)d_in[8];
    float* out = (float*)d_out;
    const int* row = eidx;
    const int* col = eidx + N_EDGES;

    char* p = (char*)d_ws;
    auto alloc = [&](size_t bytes) { char* q = p; p += (bytes + 255) & ~(size_t)255; return q; };
    // zero-init region: bucket_cnt, gsum contiguous -> ONE memset
    char* zbase = p;
    int*   bucket_cnt = (int*)alloc((size_t)NBUK * 4);
    float* gsum       = (float*)alloc((size_t)N_GRAPHS * D_H * 4);
    size_t zbytes = (size_t)(p - zbase);
    int*   bucket_base = (int*)alloc((size_t)NBUK * 4);
    int*   rowptr  = (int*)alloc((size_t)(N_NODES + 1) * 4);
    int*   gcnt    = (int*)alloc((size_t)N_GRAPHS * 4);
    float* invdeg  = (float*)alloc((size_t)N_NODES * 4);
    unsigned* edge_buf = (unsigned*)alloc((size_t)NBUK * BUK_CAP * 4);
    int*   csr_col = (int*)alloc((size_t)N_EDGES * 4);
    unsigned* xb   = (unsigned*)alloc((size_t)N_NODES * 64 * 4);   // bf16x2 packed
    unsigned* h0b  = (unsigned*)alloc((size_t)N_NODES * 64 * 4);
    unsigned* h1b  = (unsigned*)alloc((size_t)N_NODES * 64 * 4);
    unsigned short* w1p = (unsigned short*)alloc((size_t)D_IN * D_H * 2);

    (void)hipMemsetAsync(zbase, 0, zbytes, stream);

    convert_x<<<(N_NODES * 64 + 255) / 256, 256, 0, stream>>>(x, xb, N_NODES * 64);
    make_w1p<<<(D_IN * D_H) / 256, 256, 0, stream>>>(w1, w1p);
    graph_counts<<<1, 64, 0, stream>>>(batch, gcnt);

    partition_edges<<<P1_BLOCKS, 256, 0, stream>>>(row, col, bucket_cnt, edge_buf);
    scan_buckets<<<1, 256, 0, stream>>>(bucket_cnt, bucket_base);
    finalize_csr<<<NBUK, 256, 0, stream>>>(edge_buf, bucket_cnt, bucket_base,
                                           rowptr, invdeg, csr_col);

    propagate_bf16<<<(N_NODES + 3) / 4, 256, 0, stream>>>(xb,  h0b, rowptr, csr_col, invdeg);
    propagate_bf16<<<(N_NODES + 3) / 4, 256, 0, stream>>>(h0b, h1b, rowptr, csr_col, invdeg);
    propagate_bf16<<<(N_NODES + 3) / 4, 256, 0, stream>>>(h1b, h0b, rowptr, csr_col, invdeg);

    dim3 ggrid((N_NODES + 63) / 64, D_H / 128);
    gemm_mfma_pool<<<ggrid, 256, 0, stream>>>((const unsigned short*)h0b, w1p, b1, batch, gsum);
    final_mlp<<<N_GRAPHS, 256, 0, stream>>>(gsum, gcnt, w2, b2, wc, bc, out);
}

// Round 8
// 344.419 us; speedup vs baseline: 2.5485x; 1.0719x over previous
//
#include <hip/hip_runtime.h>
#include <hip/hip_bf16.h>

#define N_NODES 50000
#define N_EDGES 1600000
#define N_GRAPHS 64
#define D_IN 128
#define D_H 512
#define D_OUT 16

// atomic-free CSR build: buckets of 256 rows
#define NBUK 196                      // ceil(50000/256)
#define BUK_CAP 9216                  // per-bucket capacity: mean 8192 + ~11 sigma
#define P1_EDGES 8192                 // edges per partition block
#define P1_BLOCKS ((N_EDGES + P1_EDGES - 1) / P1_EDGES)   // 196

typedef short bf16x8 __attribute__((ext_vector_type(8)));
typedef float f32x4 __attribute__((ext_vector_type(4)));

static __device__ __forceinline__ unsigned short f2bf(float f) {
    __hip_bfloat16 h = __float2bfloat16(f);   // RNE
    return *(unsigned short*)&h;
}

// batch is SORTED: gcnt[g] = lower_bound(g+1) - lower_bound(g). 64 threads, no atomics.
__global__ __launch_bounds__(64) void graph_counts(const int* __restrict__ batch,
                                                   int* __restrict__ gcnt) {
    int g = threadIdx.x;
    int lo = 0, hi = N_NODES;
    while (lo < hi) { int mid = (lo + hi) >> 1; if (batch[mid] < g) lo = mid + 1; else hi = mid; }
    int a = lo;
    lo = 0; hi = N_NODES;
    while (lo < hi) { int mid = (lo + hi) >> 1; if (batch[mid] < g + 1) lo = mid + 1; else hi = mid; }
    gcnt[g] = lo - a;
}

// ---------------------------------------------------------------- CSR build (atomic-free)
// P1: partition edges into 196 buckets of 256 rows. Packed rec = (buk<<24)|(r_low<<16)|col.
// Only 196 global atomics per block (range reservation); ranking via LDS atomics.

__global__ __launch_bounds__(256) void partition_edges(const int* __restrict__ row,
                                                       const int* __restrict__ col,
                                                       int* __restrict__ bucket_cnt,
                                                       unsigned* __restrict__ edge_buf) {
    __shared__ unsigned recs[P1_EDGES];     // 32 KB
    __shared__ unsigned sorted[P1_EDGES];   // 32 KB
    __shared__ int hist[NBUK];              // counts, then repurposed as local excl base
    __shared__ int cur[NBUK];
    __shared__ int gbase[NBUK];
    __shared__ int scan[256];
    int tid = threadIdx.x;
    int e0 = blockIdx.x * P1_EDGES;
    int m = N_EDGES - e0; if (m > P1_EDGES) m = P1_EDGES;

    for (int i = tid; i < NBUK; i += 256) { hist[i] = 0; cur[i] = 0; }
    __syncthreads();
    for (int i = tid; i < m; i += 256) {
        int r = row[e0 + i];
        int c = col[e0 + i];
        int buk = r >> 8;
        recs[i] = ((unsigned)buk << 24) | ((unsigned)(r & 255) << 16) | (unsigned)c;
        atomicAdd(&hist[buk], 1);
    }
    __syncthreads();
    scan[tid] = (tid < NBUK) ? hist[tid] : 0;
    __syncthreads();
    for (int off = 1; off < 256; off <<= 1) {
        int v = (tid >= off) ? scan[tid - off] : 0;
        __syncthreads();
        scan[tid] += v;
        __syncthreads();
    }
    if (tid < NBUK) {
        int cnt = hist[tid];
        hist[tid] = (tid == 0) ? 0 : scan[tid - 1];            // local excl base
        gbase[tid] = (cnt > 0) ? atomicAdd(&bucket_cnt[tid], cnt) : 0;  // reserve range
    }
    __syncthreads();
    for (int i = tid; i < m; i += 256) {                       // rank + reorder (bucket-major)
        unsigned rec = recs[i];
        int buk = rec >> 24;
        int rank = atomicAdd(&cur[buk], 1);
        sorted[hist[buk] + rank] = rec;
    }
    __syncthreads();
    for (int p = tid; p < m; p += 256) {                       // coalesced-run writes
        unsigned rec = sorted[p];
        int buk = rec >> 24;
        edge_buf[(size_t)buk * BUK_CAP + gbase[buk] + (p - hist[buk])] = rec;
    }
}

__global__ __launch_bounds__(256) void scan_buckets(const int* __restrict__ bucket_cnt,
                                                    int* __restrict__ bucket_base) {
    __shared__ int scan[256];
    int tid = threadIdx.x;
    scan[tid] = (tid < NBUK) ? bucket_cnt[tid] : 0;
    __syncthreads();
    for (int off = 1; off < 256; off <<= 1) {
        int v = (tid >= off) ? scan[tid - off] : 0;
        __syncthreads();
        scan[tid] += v;
        __syncthreads();
    }
    if (tid < NBUK) bucket_base[tid] = (tid == 0) ? 0 : scan[tid - 1];
}

// P2: one block per bucket. LDS hist+scan -> rowptr/invdeg; LDS-cursor scatter into the
// bucket's contiguous 32KB csr_col window (single block -> single XCD -> full-line writebacks).
__global__ __launch_bounds__(256) void finalize_csr(const unsigned* __restrict__ edge_buf,
                                                    const int* __restrict__ bucket_cnt,
                                                    const int* __restrict__ bucket_base,
                                                    int* __restrict__ rowptr,
                                                    float* __restrict__ invdeg,
                                                    int* __restrict__ csr_col) {
    __shared__ int hist[256], excl[256], cur[256], scan[256];
    int b = blockIdx.x;
    int tid = threadIdx.x;
    int cnt = bucket_cnt[b];
    int base = bucket_base[b];
    const unsigned* src = edge_buf + (size_t)b * BUK_CAP;
    hist[tid] = 0; cur[tid] = 0;
    __syncthreads();
    for (int i = tid; i < cnt; i += 256)
        atomicAdd(&hist[(src[i] >> 16) & 255], 1);
    __syncthreads();
    scan[tid] = hist[tid];
    __syncthreads();
    for (int off = 1; off < 256; off <<= 1) {
        int v = (tid >= off) ? scan[tid - off] : 0;
        __syncthreads();
        scan[tid] += v;
        __syncthreads();
    }
    excl[tid] = (tid == 0) ? 0 : scan[tid - 1];
    __syncthreads();
    int r = b * 256 + tid;
    if (r < N_NODES) {
        rowptr[r] = base + excl[tid];
        invdeg[r] = 1.0f / (float)(hist[tid] + 1);   // +1: self loop
    }
    if (b == NBUK - 1 && tid == 0) rowptr[N_NODES] = base + cnt;
    for (int i = tid; i < cnt; i += 256) {
        unsigned rec = src[i];
        int rl = (rec >> 16) & 255;
        int pos = excl[rl] + atomicAdd(&cur[rl], 1);
        csr_col[base + pos] = (int)(rec & 0xFFFFu);
    }
}

// ---------------------------------------------------------------- converts

// x f32 [N][128] -> packed bf16x2 [N][64]
__global__ __launch_bounds__(256) void convert_x(const float* __restrict__ x,
                                                 unsigned* __restrict__ xb, int npairs) {
    int i = blockIdx.x * 256 + threadIdx.x;
    if (i < npairs) {
        float2 v = ((const float2*)x)[i];
        xb[i] = (unsigned)f2bf(v.x) | ((unsigned)f2bf(v.y) << 16);
    }
}

// w1 f32 [128][512] -> bf16 pre-swizzled to MFMA B-frag order: [t(32)][s(4)][lane(64)][j(8)]
// B[k = s*32 + (lane>>4)*8 + j][n = t*16 + (lane&15)]
__global__ __launch_bounds__(256) void make_w1p(const float* __restrict__ w1,
                                                unsigned short* __restrict__ w1p) {
    int i = blockIdx.x * 256 + threadIdx.x;     // 65536 total
    int j = i & 7, lane = (i >> 3) & 63, s = (i >> 9) & 3, t = i >> 11;
    int k = s * 32 + (lane >> 4) * 8 + j;
    int n = t * 16 + (lane & 15);
    w1p[i] = f2bf(w1[(size_t)k * D_H + n]);
}

// fold the post-pool linear layers: wcomb = w2 @ wc (512x16), bcomb = b2 @ wc + bc (16).
// grid 33 blocks x 256 threads; thread (kl,o) does one 512-dot. block 32 row = b2 -> bcomb.
__global__ __launch_bounds__(256) void fold_w(const float* __restrict__ w2,
                                              const float* __restrict__ wc,
                                              const float* __restrict__ b2,
                                              const float* __restrict__ bc,
                                              float* __restrict__ wcomb,
                                              float* __restrict__ bcomb) {
    int tid = threadIdx.x;
    int o = tid & 15, kl = tid >> 4;
    int k = blockIdx.x * 16 + kl;
    if (k > D_H) return;
    const float* wr = (k < D_H) ? (w2 + (size_t)k * D_H) : b2;
    float s = 0.f;
    for (int j = 0; j < D_H; j += 4) {
        s += wr[j + 0] * wc[(j + 0) * D_OUT + o]
           + wr[j + 1] * wc[(j + 1) * D_OUT + o]
           + wr[j + 2] * wc[(j + 2) * D_OUT + o]
           + wr[j + 3] * wc[(j + 3) * D_OUT + o];
    }
    if (k < D_H) wcomb[k * D_OUT + o] = s;
    else         bcomb[o] = s + bc[o];
}

// ---------------------------------------------------------------- propagation (bf16 storage, f32 accumulate)
// out[r] = (x[r] + sum_{r->c} x[c]) * invdeg[r]
// 4 waves/block, one row per wave; col indices shfl-broadcast from lane regs
// (no LDS, no barriers); 8 independent 256B gathers in flight.

__global__ __launch_bounds__(256) void propagate_bf16(const unsigned* __restrict__ xin,
                                                      unsigned* __restrict__ xout,
                                                      const int* __restrict__ rowptr,
                                                      const int* __restrict__ csr_col,
                                                      const float* __restrict__ invdeg) {
    int wave = threadIdx.x >> 6;
    int lane = threadIdx.x & 63;
    int r = blockIdx.x * 4 + wave;
    if (r >= N_NODES) return;
    int beg = rowptr[r], end = rowptr[r + 1];
    unsigned u = xin[(size_t)r * 64 + lane];      // self loop
    float acc0 = __uint_as_float(u << 16);
    float acc1 = __uint_as_float(u & 0xffff0000u);
    for (int cs = beg; cs < end; cs += 64) {
        int nn = end - cs; if (nn > 64) nn = 64;
        int idx = cs + (lane < nn ? lane : 0);
        int colv = csr_col[idx];
        int j = 0;
        for (; j + 8 <= nn; j += 8) {
            int c0 = __shfl(colv, j + 0, 64), c1 = __shfl(colv, j + 1, 64);
            int c2 = __shfl(colv, j + 2, 64), c3 = __shfl(colv, j + 3, 64);
            int c4 = __shfl(colv, j + 4, 64), c5 = __shfl(colv, j + 5, 64);
            int c6 = __shfl(colv, j + 6, 64), c7 = __shfl(colv, j + 7, 64);
            unsigned u0 = xin[(size_t)c0 * 64 + lane];
            unsigned u1 = xin[(size_t)c1 * 64 + lane];
            unsigned u2 = xin[(size_t)c2 * 64 + lane];
            unsigned u3 = xin[(size_t)c3 * 64 + lane];
            unsigned u4 = xin[(size_t)c4 * 64 + lane];
            unsigned u5 = xin[(size_t)c5 * 64 + lane];
            unsigned u6 = xin[(size_t)c6 * 64 + lane];
            unsigned u7 = xin[(size_t)c7 * 64 + lane];
            acc0 += __uint_as_float(u0 << 16) + __uint_as_float(u1 << 16)
                  + __uint_as_float(u2 << 16) + __uint_as_float(u3 << 16)
                  + __uint_as_float(u4 << 16) + __uint_as_float(u5 << 16)
                  + __uint_as_float(u6 << 16) + __uint_as_float(u7 << 16);
            acc1 += __uint_as_float(u0 & 0xffff0000u) + __uint_as_float(u1 & 0xffff0000u)
                  + __uint_as_float(u2 & 0xffff0000u) + __uint_as_float(u3 & 0xffff0000u)
                  + __uint_as_float(u4 & 0xffff0000u) + __uint_as_float(u5 & 0xffff0000u)
                  + __uint_as_float(u6 & 0xffff0000u) + __uint_as_float(u7 & 0xffff0000u);
        }
        for (; j < nn; ++j) {
            int c = __shfl(colv, j, 64);
            unsigned uu = xin[(size_t)c * 64 + lane];
            acc0 += __uint_as_float(uu << 16);
            acc1 += __uint_as_float(uu & 0xffff0000u);
        }
    }
    float inv = invdeg[r];
    acc0 *= inv; acc1 *= inv;
    xout[(size_t)r * 64 + lane] = (unsigned)f2bf(acc0) | ((unsigned)f2bf(acc1) << 16);
}

// ---------------------------------------------------------------- MFMA GEMM (h3 @ w1) + bias + ReLU + segmented pool
// block 256 = 4 waves; tile M=64, N=128; K=128 (4 steps of 32).
// A[m=lane&15][k=quad*8+j] direct from bf16 h3; B pre-swizzled; C: col=lane&15, row=quad*4+reg.

__global__ __launch_bounds__(256) void gemm_mfma_pool(const unsigned short* __restrict__ h3b,
                                                      const unsigned short* __restrict__ w1p,
                                                      const float* __restrict__ b1,
                                                      const int* __restrict__ batch,
                                                      float* __restrict__ gsum) {
    __shared__ float hls[64][132];   // +4 pad: conflict-free row-strided writes
    __shared__ int bls[64];
    int tid = threadIdx.x;
    int lane = tid & 63, wave = tid >> 6;
    int quad = lane >> 4, l15 = lane & 15;
    int mbase = blockIdx.x * 64;
    int nbase = blockIdx.y * 128;

    int m = mbase + wave * 16 + l15;
    int mc = m < N_NODES ? m : N_NODES - 1;          // clamp; garbage rows skipped in epilogue
    const unsigned short* arow = h3b + (size_t)mc * 128 + quad * 8;
    bf16x8 afrag[4];
#pragma unroll
    for (int s = 0; s < 4; ++s)
        afrag[s] = *(const bf16x8*)(arow + s * 32);

    f32x4 acc[8];
#pragma unroll
    for (int t = 0; t < 8; ++t) acc[t] = (f32x4){0.f, 0.f, 0.f, 0.f};

    const unsigned short* bbase = w1p + ((size_t)(blockIdx.y * 8) * 4 * 64 + lane) * 8;
#pragma unroll
    for (int t = 0; t < 8; ++t) {
#pragma unroll
        for (int s = 0; s < 4; ++s) {
            bf16x8 bfrag = *(const bf16x8*)(bbase + (size_t)(t * 4 + s) * 64 * 8);
            acc[t] = __builtin_amdgcn_mfma_f32_16x16x32_bf16(afrag[s], bfrag, acc[t], 0, 0, 0);
        }
    }

    if (tid < 64) {
        int mm = mbase + tid;
        bls[tid] = (mm < N_NODES) ? batch[mm] : 0;
    }
#pragma unroll
    for (int t = 0; t < 8; ++t)
#pragma unroll
        for (int rg = 0; rg < 4; ++rg)
            hls[wave * 16 + quad * 4 + rg][t * 16 + l15] = acc[t][rg];
    __syncthreads();

    // epilogue: bias + relu + sorted-segment pool; thread owns (col, 32-row half)
    int c = tid & 127, half = tid >> 7;
    float bias = b1[nbase + c];
    int r0 = half * 32;
    int cur = bls[r0];
    float s = 0.f;
    for (int r = r0; r < r0 + 32; ++r) {
        int mm = mbase + r;
        if (mm >= N_NODES) break;
        int g = bls[r];
        float v = hls[r][c] + bias;
        v = v > 0.f ? v : 0.f;
        if (g != cur) { atomicAdd(&gsum[cur * D_H + nbase + c], s); s = 0.f; cur = g; }
        s += v;
    }
    atomicAdd(&gsum[cur * D_H + nbase + c], s);
}

// ---------------------------------------------------------------- final: mean + (512x16) folded projection, one block per graph

__global__ __launch_bounds__(256) void final_pool(const float* __restrict__ gsum,
                                                  const int* __restrict__ gcnt,
                                                  const float* __restrict__ wcomb,
                                                  const float* __restrict__ bcomb,
                                                  float* __restrict__ out) {
    int g = blockIdx.x;
    int tid = threadIdx.x;
    __shared__ float p[D_H];
    __shared__ float part[16][17];
    int c = gcnt[g]; if (c < 1) c = 1;
    float inv = 1.0f / (float)c;
    p[tid] = gsum[g * D_H + tid] * inv;
    p[tid + 256] = gsum[g * D_H + tid + 256] * inv;
    __syncthreads();
    int o = tid & 15, ch = tid >> 4;
    int k0 = ch * 32;
    float s = 0.f;
    for (int k = k0; k < k0 + 32; ++k)
        s += p[k] * wcomb[k * D_OUT + o];
    part[ch][o] = s;
    __syncthreads();
    if (tid < D_OUT) {
        float t = bcomb[tid];
        for (int ch2 = 0; ch2 < 16; ++ch2) t += part[ch2][tid];
        out[g * D_OUT + tid] = t;
    }
}

// ---------------------------------------------------------------- launch

extern "C" void kernel_launch(void* const* d_in, const int* in_sizes, int n_in,
                              void* d_out, int out_size, void* d_ws, size_t ws_size,
                              hipStream_t stream) {
    const float* x     = (const float*)d_in[0];
    const int*   eidx  = (const int*)d_in[1];   // [2, E]
    const int*   batch = (const int*)d_in[2];
    const float* w1    = (const float*)d_in[3];
    const float* b1    = (const float*)d_in[4];
    const float* w2    = (const float*)d_in[5];
    const float* b2    = (const float*)d_in[6];
    const float* wc    = (const float*)d_in[7];
    const float* bc    = (const float*)d_in[8];
    float* out = (float*)d_out;
    const int* row = eidx;
    const int* col = eidx + N_EDGES;

    char* p = (char*)d_ws;
    auto alloc = [&](size_t bytes) { char* q = p; p += (bytes + 255) & ~(size_t)255; return q; };
    // zero-init region: bucket_cnt, gsum contiguous -> ONE memset
    char* zbase = p;
    int*   bucket_cnt = (int*)alloc((size_t)NBUK * 4);
    float* gsum       = (float*)alloc((size_t)N_GRAPHS * D_H * 4);
    size_t zbytes = (size_t)(p - zbase);
    int*   bucket_base = (int*)alloc((size_t)NBUK * 4);
    int*   rowptr  = (int*)alloc((size_t)(N_NODES + 1) * 4);
    int*   gcnt    = (int*)alloc((size_t)N_GRAPHS * 4);
    float* invdeg  = (float*)alloc((size_t)N_NODES * 4);
    float* wcomb   = (float*)alloc((size_t)D_H * D_OUT * 4);
    float* bcomb   = (float*)alloc((size_t)D_OUT * 4);
    unsigned* edge_buf = (unsigned*)alloc((size_t)NBUK * BUK_CAP * 4);
    int*   csr_col = (int*)alloc((size_t)N_EDGES * 4);
    unsigned* xb   = (unsigned*)alloc((size_t)N_NODES * 64 * 4);   // bf16x2 packed
    unsigned* h0b  = (unsigned*)alloc((size_t)N_NODES * 64 * 4);
    unsigned* h1b  = (unsigned*)alloc((size_t)N_NODES * 64 * 4);
    unsigned short* w1p = (unsigned short*)alloc((size_t)D_IN * D_H * 2);

    (void)hipMemsetAsync(zbase, 0, zbytes, stream);

    convert_x<<<(N_NODES * 64 + 255) / 256, 256, 0, stream>>>(x, xb, N_NODES * 64);
    make_w1p<<<(D_IN * D_H) / 256, 256, 0, stream>>>(w1, w1p);
    fold_w<<<33, 256, 0, stream>>>(w2, wc, b2, bc, wcomb, bcomb);
    graph_counts<<<1, 64, 0, stream>>>(batch, gcnt);

    partition_edges<<<P1_BLOCKS, 256, 0, stream>>>(row, col, bucket_cnt, edge_buf);
    scan_buckets<<<1, 256, 0, stream>>>(bucket_cnt, bucket_base);
    finalize_csr<<<NBUK, 256, 0, stream>>>(edge_buf, bucket_cnt, bucket_base,
                                           rowptr, invdeg, csr_col);

    propagate_bf16<<<(N_NODES + 3) / 4, 256, 0, stream>>>(xb,  h0b, rowptr, csr_col, invdeg);
    propagate_bf16<<<(N_NODES + 3) / 4, 256, 0, stream>>>(h0b, h1b, rowptr, csr_col, invdeg);
    propagate_bf16<<<(N_NODES + 3) / 4, 256, 0, stream>>>(h1b, h0b, rowptr, csr_col, invdeg);

    dim3 ggrid((N_NODES + 63) / 64, D_H / 128);
    gemm_mfma_pool<<<ggrid, 256, 0, stream>>>((const unsigned short*)h0b, w1p, b1, batch, gsum);
    final_pool<<<N_GRAPHS, 256, 0, stream>>>(gsum, gcnt, wcomb, bcomb, out);
}